// Round 4
// baseline (363.633 us; speedup 1.0000x reference)
//
#include <hip/hip_runtime.h>
#include <math.h>

#define N_NODES 8192
#define F_IN    512
#define H1      32
#define H2      16

#define FMA4(acc, s, v) do { (acc).x += (s)*(v).x; (acc).y += (s)*(v).y; \
                             (acc).z += (s)*(v).z; (acc).w += (s)*(v).w; } while(0)

#define RED4(a) do { \
        (a).x += __shfl_xor((a).x, 4); (a).y += __shfl_xor((a).y, 4); \
        (a).z += __shfl_xor((a).z, 4); (a).w += __shfl_xor((a).w, 4); \
        (a).x += __shfl_xor((a).x, 8); (a).y += __shfl_xor((a).y, 8); \
        (a).z += __shfl_xor((a).z, 8); (a).w += __shfl_xor((a).w, 8); } while(0)

// ---------------- Kernel 1: XW0 = features @ W0  (+ zero cnt for the CSR hist) ----------------
__global__ __launch_bounds__(256) void k_xw0(const float* __restrict__ feat,
                                             const float* __restrict__ W0,
                                             float* __restrict__ xw0,
                                             int* __restrict__ cnt) {
    int t = threadIdx.x;
    int gid = blockIdx.x * 256 + t;
    if (gid < N_NODES) cnt[gid] = 0;            // zero histogram (next kernel boundary syncs)

    __shared__ float w0s[F_IN * H1];            // 64 KiB
    float4* w0s_v = (float4*)w0s;
    const float4* W0_v = (const float4*)W0;
    #pragma unroll
    for (int i = 0; i < 16; ++i) w0s_v[t + i * 256] = W0_v[t + i * 256];
    __syncthreads();

    int row = blockIdx.x * 32 + (t >> 3);       // 32 rows / block
    int cg  = (t & 7) * 4;                      // 4 cols / thread
    const float4* frow_v = (const float4*)(feat + (size_t)row * F_IN);

    float4 acc = {0.f, 0.f, 0.f, 0.f};
    #pragma unroll 4
    for (int k0 = 0; k0 < F_IN; k0 += 4) {
        float4 f  = frow_v[k0 >> 2];
        float4 w0 = *(float4*)&w0s[(k0 + 0) * H1 + cg];
        float4 w1 = *(float4*)&w0s[(k0 + 1) * H1 + cg];
        float4 w2 = *(float4*)&w0s[(k0 + 2) * H1 + cg];
        float4 w3 = *(float4*)&w0s[(k0 + 3) * H1 + cg];
        FMA4(acc, f.x, w0);
        FMA4(acc, f.y, w1);
        FMA4(acc, f.z, w2);
        FMA4(acc, f.w, w3);
    }
    *(float4*)&xw0[row * H1 + cg] = acc;
}

// ---------------- CSR build: histogram -> scan -> scatter ----------------
__global__ __launch_bounds__(256) void k_hist(const int* __restrict__ rows,
                                              int* __restrict__ cnt, int E) {
    int e = blockIdx.x * 256 + threadIdx.x;
    if (e < E) atomicAdd(&cnt[rows[e]], 1);
}

__global__ __launch_bounds__(256) void k_scan(const int* __restrict__ cnt,
                                              int* __restrict__ row_start,
                                              int* __restrict__ cursor) {
    __shared__ int buf[N_NODES + 256];          // skewed: phys = v + (v>>5)
    __shared__ int part[256];
    int t = threadIdx.x;
    #pragma unroll
    for (int i = 0; i < 32; ++i) {              // coalesced global read, skewed LDS write
        int v = t + i * 256;
        buf[v + (v >> 5)] = cnt[v];
    }
    __syncthreads();
    int base = t * 32;
    int local[32];
    int s = 0;
    #pragma unroll
    for (int i = 0; i < 32; ++i) { local[i] = buf[33 * t + i]; s += local[i]; }
    part[t] = s;
    __syncthreads();
    for (int off = 1; off < 256; off <<= 1) {
        int v = (t >= off) ? part[t - off] : 0;
        __syncthreads();
        part[t] += v;
        __syncthreads();
    }
    int run = (t == 0) ? 0 : part[t - 1];       // exclusive base for this chunk
    #pragma unroll
    for (int i = 0; i < 32; ++i) {
        row_start[base + i] = run;
        cursor[base + i]    = run;
        run += local[i];
    }
    if (t == 255) row_start[N_NODES] = run;
}

__global__ __launch_bounds__(256) void k_scatter(const int* __restrict__ rows,
                                                 const int* __restrict__ cols,
                                                 const float* __restrict__ vals,
                                                 int* __restrict__ cursor,
                                                 int2* __restrict__ edges, int E) {
    int e = blockIdx.x * 256 + threadIdx.x;
    if (e >= E) return;
    int pos = atomicAdd(&cursor[rows[e]], 1);
    edges[pos] = make_int2(cols[e], __float_as_int(vals[e]));
}

// ------- Kernel 2: Y[N][48] = relu(A @ XW0) @ {W1,W2,W3}  (SpMM gather + fused heads) -------
__global__ __launch_bounds__(256) void k_spmm1h(const int* __restrict__ row_start,
                                                const int2* __restrict__ edges,
                                                const float* __restrict__ xw0,
                                                const float* __restrict__ W1,
                                                const float* __restrict__ W2,
                                                const float* __restrict__ W3,
                                                float* __restrict__ Y) {
    __shared__ float ws[3 * H1 * H2];           // 6 KiB
    int t = threadIdx.x;
    for (int i = t; i < H1 * H2; i += 256) {
        ws[i]        = W1[i];
        ws[512 + i]  = W2[i];
        ws[1024 + i] = W3[i];
    }
    __syncthreads();

    int g  = blockIdx.x * 256 + t;
    int r  = g >> 4;
    int tt = t & 15;
    int part = (tt & 7) * 4;                    // which float4 of the 32-wide h1 row
    int half = tt >> 3;                         // edge-split factor 2
    int s = row_start[r], e = row_start[r + 1];
    float4 acc = {0.f, 0.f, 0.f, 0.f};
    for (int i = s + half; i < e; i += 2) {
        int2 ed = edges[i];
        float v = __int_as_float(ed.y);
        float4 x = *(const float4*)&xw0[ed.x * H1 + part];
        FMA4(acc, v, x);
    }
    // butterfly: after this BOTH halves hold the reduced h1[part..part+3]
    acc.x += __shfl_xor(acc.x, 8);
    acc.y += __shfl_xor(acc.y, 8);
    acc.z += __shfl_xor(acc.z, 8);
    acc.w += __shfl_xor(acc.w, 8);
    acc.x = fmaxf(acc.x, 0.f); acc.y = fmaxf(acc.y, 0.f);
    acc.z = fmaxf(acc.z, 0.f); acc.w = fmaxf(acc.w, 0.f);

    // heads: lane tt computes col tt of each of the 3 heads
    float a0 = 0.f, a1 = 0.f, a2 = 0.f;
    #pragma unroll
    for (int sI = 0; sI < 8; ++sI) {            // lane sI holds h1[sI*4 .. sI*4+3]
        float hx = __shfl(acc.x, sI, 16);
        float hy = __shfl(acc.y, sI, 16);
        float hz = __shfl(acc.z, sI, 16);
        float hw = __shfl(acc.w, sI, 16);
        int k = sI * 4;
        a0 += hx * ws[(k+0)*16 + tt]        + hy * ws[(k+1)*16 + tt]
            + hz * ws[(k+2)*16 + tt]        + hw * ws[(k+3)*16 + tt];
        a1 += hx * ws[512 + (k+0)*16 + tt]  + hy * ws[512 + (k+1)*16 + tt]
            + hz * ws[512 + (k+2)*16 + tt]  + hw * ws[512 + (k+3)*16 + tt];
        a2 += hx * ws[1024 + (k+0)*16 + tt] + hy * ws[1024 + (k+1)*16 + tt]
            + hz * ws[1024 + (k+2)*16 + tt] + hw * ws[1024 + (k+3)*16 + tt];
    }
    float* yr = &Y[r * 48];
    yr[tt]      = a0;
    yr[16 + tt] = a1;
    yr[32 + tt] = a2;
}

// ------- Kernel 3: z = spmm3 + double softmax + reparameterization (fused) -------
__global__ __launch_bounds__(256) void k_spmm3f(const int* __restrict__ row_start,
                                                const int2* __restrict__ edges,
                                                const float* __restrict__ Y,
                                                const float* __restrict__ s1,
                                                const float* __restrict__ s2,
                                                float* __restrict__ z) {
    int t  = blockIdx.x * 256 + threadIdx.x;
    int r  = t >> 4;
    int tt = t & 15;
    int cg = (tt & 3) * 4;                      // which float4 of each head's 16
    int q  = tt >> 2;                           // edge-split factor 4
    int s = row_start[r], e = row_start[r + 1];
    float4 a0 = {0,0,0,0}, a1 = {0,0,0,0}, a2 = {0,0,0,0};
    for (int i = s + q; i < e; i += 4) {
        int2 ed = edges[i];
        float v = __int_as_float(ed.y);
        const float* y = &Y[ed.x * 48];
        FMA4(a0, v, *(const float4*)&y[cg]);
        FMA4(a1, v, *(const float4*)&y[16 + cg]);
        FMA4(a2, v, *(const float4*)&y[32 + cg]);
    }
    RED4(a0); RED4(a1); RED4(a2);               // all 16 lanes now hold sums for their cg

    // softmax over the 16 cols of head1 (a1) and head2 (a2): 4 lanes x 4 vals per quad
    float m1 = fmaxf(fmaxf(a1.x, a1.y), fmaxf(a1.z, a1.w));
    m1 = fmaxf(m1, __shfl_xor(m1, 1));
    m1 = fmaxf(m1, __shfl_xor(m1, 2));
    float m2 = fmaxf(fmaxf(a2.x, a2.y), fmaxf(a2.z, a2.w));
    m2 = fmaxf(m2, __shfl_xor(m2, 1));
    m2 = fmaxf(m2, __shfl_xor(m2, 2));

    float4 e1, e2;
    e1.x = expf(a1.x - m1); e1.y = expf(a1.y - m1);
    e1.z = expf(a1.z - m1); e1.w = expf(a1.w - m1);
    e2.x = expf(a2.x - m2); e2.y = expf(a2.y - m2);
    e2.z = expf(a2.z - m2); e2.w = expf(a2.w - m2);
    float sum1 = e1.x + e1.y + e1.z + e1.w;
    sum1 += __shfl_xor(sum1, 1); sum1 += __shfl_xor(sum1, 2);
    float sum2 = e2.x + e2.y + e2.z + e2.w;
    sum2 += __shfl_xor(sum2, 1); sum2 += __shfl_xor(sum2, 2);
    float inv1 = 1.f / sum1, inv2 = 1.f / sum2;

    float4 sv1 = *(const float4*)&s1[r * H2 + cg];
    float4 sv2 = *(const float4*)&s2[r * H2 + cg];
    float4 zr;
    zr.x = a0.x + sv2.x * (expf(e1.x * inv1) + sv1.x * 0.1f * expf(e2.x * inv2));
    zr.y = a0.y + sv2.y * (expf(e1.y * inv1) + sv1.y * 0.1f * expf(e2.y * inv2));
    zr.z = a0.z + sv2.z * (expf(e1.z * inv1) + sv1.z * 0.1f * expf(e2.z * inv2));
    zr.w = a0.w + sv2.w * (expf(e1.w * inv1) + sv1.w * 0.1f * expf(e2.w * inv2));
    if (q == 0) *(float4*)&z[r * H2 + cg] = zr;
}

// ---------------- Kernel 4: out = z @ z^T  (64x64 tiles, 4x4 per thread) ----------------
__global__ __launch_bounds__(256) void k_zzt(const float* __restrict__ z,
                                             float* __restrict__ out) {
    __shared__ float zi[64 * 17];    // padded rows: conflict-free scalar a-reads
    __shared__ float zjT[H2 * 64];   // transposed: conflict-free float4 b-reads
    int t  = threadIdx.x;
    int i0 = blockIdx.y * 64, j0 = blockIdx.x * 64;

    {   // stage: each thread moves one float4 for zi and one for zjT
        int c = t >> 2, qq = (t & 3) * 4;
        float4 a = *(const float4*)&z[(i0 + c) * H2 + qq];
        zi[c * 17 + qq + 0] = a.x; zi[c * 17 + qq + 1] = a.y;
        zi[c * 17 + qq + 2] = a.z; zi[c * 17 + qq + 3] = a.w;
        float4 b = *(const float4*)&z[(j0 + c) * H2 + qq];
        zjT[(qq + 0) * 64 + c] = b.x; zjT[(qq + 1) * 64 + c] = b.y;
        zjT[(qq + 2) * 64 + c] = b.z; zjT[(qq + 3) * 64 + c] = b.w;
    }
    __syncthreads();

    int tx = t & 15, ty = t >> 4;
    float4 acc0 = {0,0,0,0}, acc1 = {0,0,0,0}, acc2 = {0,0,0,0}, acc3 = {0,0,0,0};
    const float4* zjT_v = (const float4*)zjT;
    #pragma unroll
    for (int k = 0; k < H2; ++k) {
        float4 b  = zjT_v[k * 16 + tx];
        float  a0 = zi[(ty * 4 + 0) * 17 + k];
        float  a1 = zi[(ty * 4 + 1) * 17 + k];
        float  a2 = zi[(ty * 4 + 2) * 17 + k];
        float  a3 = zi[(ty * 4 + 3) * 17 + k];
        FMA4(acc0, a0, b);
        FMA4(acc1, a1, b);
        FMA4(acc2, a2, b);
        FMA4(acc3, a3, b);
    }
    size_t base = (size_t)(i0 + ty * 4) * N_NODES + j0 + tx * 4;
    *(float4*)&out[base]               = acc0;
    *(float4*)&out[base + N_NODES]     = acc1;
    *(float4*)&out[base + 2 * N_NODES] = acc2;
    *(float4*)&out[base + 3 * N_NODES] = acc3;
}

// ---------------- Launch ----------------
extern "C" void kernel_launch(void* const* d_in, const int* in_sizes, int n_in,
                              void* d_out, int out_size, void* d_ws, size_t ws_size,
                              hipStream_t stream) {
    const float* feat = (const float*)d_in[0];
    const int*   rows = (const int*)d_in[1];
    const int*   cols = (const int*)d_in[2];
    const float* vals = (const float*)d_in[3];
    const float* W0   = (const float*)d_in[4];
    const float* W1   = (const float*)d_in[5];
    const float* W2   = (const float*)d_in[6];
    const float* W3   = (const float*)d_in[7];
    const float* s1   = (const float*)d_in[8];
    const float* s2   = (const float*)d_in[9];
    float* out = (float*)d_out;
    int E = in_sizes[1];

    float* ws        = (float*)d_ws;
    float* xw0       = ws;                     // 262144 floats
    float* Y         = ws + 262144;            // N*48 = 393216 floats
    float* z         = ws + 655360;            // 131072 floats
    int*   cnt       = (int*)(ws + 786432);    // 8192 ints
    int*   row_start = (int*)(ws + 794624);    // 8193 ints used, 8448 reserved
    int*   cursor    = (int*)(ws + 803072);    // 8192 ints
    int2*  edges     = (int2*)(ws + 811264);   // E int2 (8B-aligned: 811264*4 % 8 == 0)

    k_xw0    <<<N_NODES / 32, 256, 0, stream>>>(feat, W0, xw0, cnt);
    k_hist   <<<(E + 255) / 256, 256, 0, stream>>>(rows, cnt, E);
    k_scan   <<<1, 256, 0, stream>>>(cnt, row_start, cursor);
    k_scatter<<<(E + 255) / 256, 256, 0, stream>>>(rows, cols, vals, cursor, edges, E);
    k_spmm1h <<<N_NODES * 16 / 256, 256, 0, stream>>>(row_start, edges, xw0, W1, W2, W3, Y);
    k_spmm3f <<<N_NODES * 16 / 256, 256, 0, stream>>>(row_start, edges, Y, s1, s2, z);

    dim3 grid(N_NODES / 64, N_NODES / 64);
    k_zzt<<<grid, 256, 0, stream>>>(z, out);
}

// Round 5
// 341.949 us; speedup vs baseline: 1.0634x; 1.0634x over previous
//
#include <hip/hip_runtime.h>
#include <math.h>

#define N_NODES 8192
#define F_IN    512
#define H1      32
#define H2      16
#define ELLW    64

#define FMA4(acc, s, v) do { (acc).x += (s)*(v).x; (acc).y += (s)*(v).y; \
                             (acc).z += (s)*(v).z; (acc).w += (s)*(v).w; } while(0)

#define RED4(a) do { \
        (a).x += __shfl_xor((a).x, 4); (a).y += __shfl_xor((a).y, 4); \
        (a).z += __shfl_xor((a).z, 4); (a).w += __shfl_xor((a).w, 4); \
        (a).x += __shfl_xor((a).x, 8); (a).y += __shfl_xor((a).y, 8); \
        (a).z += __shfl_xor((a).z, 8); (a).w += __shfl_xor((a).w, 8); } while(0)

// ---------------- Kernel 1: XW0 = features @ W0  (+ zero deg for the ELL scatter) ----------------
__global__ __launch_bounds__(256) void k_xw0(const float* __restrict__ feat,
                                             const float* __restrict__ W0,
                                             float* __restrict__ xw0,
                                             int* __restrict__ deg) {
    int t = threadIdx.x;
    int gid = blockIdx.x * 256 + t;
    if (gid < N_NODES) deg[gid] = 0;            // zero ELL degree (next kernel boundary syncs)

    __shared__ float w0s[F_IN * H1];            // 64 KiB
    float4* w0s_v = (float4*)w0s;
    const float4* W0_v = (const float4*)W0;
    #pragma unroll
    for (int i = 0; i < 16; ++i) w0s_v[t + i * 256] = W0_v[t + i * 256];
    __syncthreads();

    int row = blockIdx.x * 32 + (t >> 3);       // 32 rows / block
    int cg  = (t & 7) * 4;                      // 4 cols / thread
    const float4* frow_v = (const float4*)(feat + (size_t)row * F_IN);

    float4 acc = {0.f, 0.f, 0.f, 0.f};
    #pragma unroll 4
    for (int k0 = 0; k0 < F_IN; k0 += 4) {
        float4 f  = frow_v[k0 >> 2];
        float4 w0 = *(float4*)&w0s[(k0 + 0) * H1 + cg];
        float4 w1 = *(float4*)&w0s[(k0 + 1) * H1 + cg];
        float4 w2 = *(float4*)&w0s[(k0 + 2) * H1 + cg];
        float4 w3 = *(float4*)&w0s[(k0 + 3) * H1 + cg];
        FMA4(acc, f.x, w0);
        FMA4(acc, f.y, w1);
        FMA4(acc, f.z, w2);
        FMA4(acc, f.w, w3);
    }
    *(float4*)&xw0[row * H1 + cg] = acc;
}

// ---------------- Kernel 2: one-pass ELL build (replaces hist+scan+scatter) ----------------
__global__ __launch_bounds__(256) void k_scatter_ell(const int* __restrict__ rows,
                                                     const int* __restrict__ cols,
                                                     const float* __restrict__ vals,
                                                     int* __restrict__ deg,
                                                     int2* __restrict__ ell, int E) {
    int e = blockIdx.x * 256 + threadIdx.x;
    if (e >= E) return;
    int r = rows[e];
    int slot = atomicAdd(&deg[r], 1);
    if (slot < ELLW)                            // P(deg>64) ~ 1e-18 for Poisson(16); guard anyway
        ell[r * ELLW + slot] = make_int2(cols[e], __float_as_int(vals[e]));
}

// ------- Kernel 3: Y[N][48] = relu(A @ XW0) @ {W1,W2,W3}  (ELL gather + fused heads) -------
__global__ __launch_bounds__(256) void k_spmm1h(const int* __restrict__ deg,
                                                const int2* __restrict__ ell,
                                                const float* __restrict__ xw0,
                                                const float* __restrict__ W1,
                                                const float* __restrict__ W2,
                                                const float* __restrict__ W3,
                                                float* __restrict__ Y) {
    __shared__ float ws[3 * H1 * H2];           // 6 KiB
    int t = threadIdx.x;
    for (int i = t; i < H1 * H2; i += 256) {
        ws[i]        = W1[i];
        ws[512 + i]  = W2[i];
        ws[1024 + i] = W3[i];
    }
    __syncthreads();

    int g  = blockIdx.x * 256 + t;
    int r  = g >> 4;
    int tt = t & 15;
    int part = (tt & 7) * 4;                    // which float4 of the 32-wide h1 row
    int half = tt >> 3;                         // edge-split factor 2
    int dr = min(deg[r], ELLW);
    const int2* er = &ell[r * ELLW];
    float4 acc = {0.f, 0.f, 0.f, 0.f};
    for (int i = half; i < dr; i += 2) {
        int2 ed = er[i];
        float v = __int_as_float(ed.y);
        float4 x = *(const float4*)&xw0[ed.x * H1 + part];
        FMA4(acc, v, x);
    }
    // butterfly: after this BOTH halves hold the reduced h1[part..part+3]
    acc.x += __shfl_xor(acc.x, 8);
    acc.y += __shfl_xor(acc.y, 8);
    acc.z += __shfl_xor(acc.z, 8);
    acc.w += __shfl_xor(acc.w, 8);
    acc.x = fmaxf(acc.x, 0.f); acc.y = fmaxf(acc.y, 0.f);
    acc.z = fmaxf(acc.z, 0.f); acc.w = fmaxf(acc.w, 0.f);

    // heads: lane tt computes col tt of each of the 3 heads
    float a0 = 0.f, a1 = 0.f, a2 = 0.f;
    #pragma unroll
    for (int sI = 0; sI < 8; ++sI) {            // lane sI holds h1[sI*4 .. sI*4+3]
        float hx = __shfl(acc.x, sI, 16);
        float hy = __shfl(acc.y, sI, 16);
        float hz = __shfl(acc.z, sI, 16);
        float hw = __shfl(acc.w, sI, 16);
        int k = sI * 4;
        a0 += hx * ws[(k+0)*16 + tt]        + hy * ws[(k+1)*16 + tt]
            + hz * ws[(k+2)*16 + tt]        + hw * ws[(k+3)*16 + tt];
        a1 += hx * ws[512 + (k+0)*16 + tt]  + hy * ws[512 + (k+1)*16 + tt]
            + hz * ws[512 + (k+2)*16 + tt]  + hw * ws[512 + (k+3)*16 + tt];
        a2 += hx * ws[1024 + (k+0)*16 + tt] + hy * ws[1024 + (k+1)*16 + tt]
            + hz * ws[1024 + (k+2)*16 + tt] + hw * ws[1024 + (k+3)*16 + tt];
    }
    float* yr = &Y[r * 48];
    yr[tt]      = a0;
    yr[16 + tt] = a1;
    yr[32 + tt] = a2;
}

// ------- Kernel 4: z = spmm3 + double softmax + reparameterization (ELL gather, fused) -------
__global__ __launch_bounds__(256) void k_spmm3f(const int* __restrict__ deg,
                                                const int2* __restrict__ ell,
                                                const float* __restrict__ Y,
                                                const float* __restrict__ s1,
                                                const float* __restrict__ s2,
                                                float* __restrict__ z) {
    int t  = blockIdx.x * 256 + threadIdx.x;
    int r  = t >> 4;
    int tt = t & 15;
    int cg = (tt & 3) * 4;                      // which float4 of each head's 16
    int q  = tt >> 2;                           // edge-split factor 4
    int dr = min(deg[r], ELLW);
    const int2* er = &ell[r * ELLW];
    float4 a0 = {0,0,0,0}, a1 = {0,0,0,0}, a2 = {0,0,0,0};
    for (int i = q; i < dr; i += 4) {
        int2 ed = er[i];
        float v = __int_as_float(ed.y);
        const float* y = &Y[ed.x * 48];
        FMA4(a0, v, *(const float4*)&y[cg]);
        FMA4(a1, v, *(const float4*)&y[16 + cg]);
        FMA4(a2, v, *(const float4*)&y[32 + cg]);
    }
    RED4(a0); RED4(a1); RED4(a2);               // all 16 lanes now hold sums for their cg

    // softmax over the 16 cols of head1 (a1) and head2 (a2): 4 lanes x 4 vals per quad
    float m1 = fmaxf(fmaxf(a1.x, a1.y), fmaxf(a1.z, a1.w));
    m1 = fmaxf(m1, __shfl_xor(m1, 1));
    m1 = fmaxf(m1, __shfl_xor(m1, 2));
    float m2 = fmaxf(fmaxf(a2.x, a2.y), fmaxf(a2.z, a2.w));
    m2 = fmaxf(m2, __shfl_xor(m2, 1));
    m2 = fmaxf(m2, __shfl_xor(m2, 2));

    float4 e1, e2;
    e1.x = expf(a1.x - m1); e1.y = expf(a1.y - m1);
    e1.z = expf(a1.z - m1); e1.w = expf(a1.w - m1);
    e2.x = expf(a2.x - m2); e2.y = expf(a2.y - m2);
    e2.z = expf(a2.z - m2); e2.w = expf(a2.w - m2);
    float sum1 = e1.x + e1.y + e1.z + e1.w;
    sum1 += __shfl_xor(sum1, 1); sum1 += __shfl_xor(sum1, 2);
    float sum2 = e2.x + e2.y + e2.z + e2.w;
    sum2 += __shfl_xor(sum2, 1); sum2 += __shfl_xor(sum2, 2);
    float inv1 = 1.f / sum1, inv2 = 1.f / sum2;

    float4 sv1 = *(const float4*)&s1[r * H2 + cg];
    float4 sv2 = *(const float4*)&s2[r * H2 + cg];
    float4 zr;
    zr.x = a0.x + sv2.x * (expf(e1.x * inv1) + sv1.x * 0.1f * expf(e2.x * inv2));
    zr.y = a0.y + sv2.y * (expf(e1.y * inv1) + sv1.y * 0.1f * expf(e2.y * inv2));
    zr.z = a0.z + sv2.z * (expf(e1.z * inv1) + sv1.z * 0.1f * expf(e2.z * inv2));
    zr.w = a0.w + sv2.w * (expf(e1.w * inv1) + sv1.w * 0.1f * expf(e2.w * inv2));
    if (q == 0) *(float4*)&z[r * H2 + cg] = zr;
}

// -------- Kernel 5: out = z @ z^T  (16x256 tiles; wave-wide 1 KB contiguous stores) --------
__global__ __launch_bounds__(256) void k_zzt(const float* __restrict__ z,
                                             float* __restrict__ out) {
    __shared__ float zi[16 * 16];               // A tile, row-major (b128 broadcast reads)
    __shared__ float zjT[H2 * 256];             // B tile transposed: [k][col] (linear b128 reads)
    int t  = threadIdx.x;
    int i0 = blockIdx.y * 16, j0 = blockIdx.x * 256;

    if (t < 64) {                               // stage A: 16 rows x 16 floats
        int r = t >> 2, q = t & 3;
        ((float4*)zi)[r * 4 + q] = ((const float4*)z)[(i0 + r) * 4 + q];
    }
    {                                           // stage B transposed: thread t owns col t
        const float4* zr = (const float4*)&z[(size_t)(j0 + t) * H2];
        #pragma unroll
        for (int q4 = 0; q4 < 4; ++q4) {
            float4 f = zr[q4];
            zjT[(q4 * 4 + 0) * 256 + t] = f.x;
            zjT[(q4 * 4 + 1) * 256 + t] = f.y;
            zjT[(q4 * 4 + 2) * 256 + t] = f.z;
            zjT[(q4 * 4 + 3) * 256 + t] = f.w;
        }
    }
    __syncthreads();

    int tx = t & 63, ty = t >> 6;               // wave ty owns rows i0+ty*4..+3
    const float4* ziv = (const float4*)zi;
    const float4* zjv = (const float4*)zjT;
    float4 acc0 = {0,0,0,0}, acc1 = {0,0,0,0}, acc2 = {0,0,0,0}, acc3 = {0,0,0,0};
    #pragma unroll
    for (int k4 = 0; k4 < 4; ++k4) {
        float4 a0 = ziv[(ty * 4 + 0) * 4 + k4];     // broadcast within wave
        float4 a1 = ziv[(ty * 4 + 1) * 4 + k4];
        float4 a2 = ziv[(ty * 4 + 2) * 4 + k4];
        float4 a3 = ziv[(ty * 4 + 3) * 4 + k4];
        float4 b0 = zjv[(k4 * 4 + 0) * 64 + tx];    // 64 lanes linear -> conflict-free
        float4 b1 = zjv[(k4 * 4 + 1) * 64 + tx];
        float4 b2 = zjv[(k4 * 4 + 2) * 64 + tx];
        float4 b3 = zjv[(k4 * 4 + 3) * 64 + tx];
        FMA4(acc0, a0.x, b0); FMA4(acc0, a0.y, b1); FMA4(acc0, a0.z, b2); FMA4(acc0, a0.w, b3);
        FMA4(acc1, a1.x, b0); FMA4(acc1, a1.y, b1); FMA4(acc1, a1.z, b2); FMA4(acc1, a1.w, b3);
        FMA4(acc2, a2.x, b0); FMA4(acc2, a2.y, b1); FMA4(acc2, a2.z, b2); FMA4(acc2, a2.w, b3);
        FMA4(acc3, a3.x, b0); FMA4(acc3, a3.y, b1); FMA4(acc3, a3.z, b2); FMA4(acc3, a3.w, b3);
    }
    size_t base = (size_t)(i0 + ty * 4) * N_NODES + j0 + tx * 4;
    *(float4*)&out[base]               = acc0;   // each store instr: wave-wide 1 KB contiguous
    *(float4*)&out[base + N_NODES]     = acc1;
    *(float4*)&out[base + 2 * N_NODES] = acc2;
    *(float4*)&out[base + 3 * N_NODES] = acc3;
}

// ---------------- Launch ----------------
extern "C" void kernel_launch(void* const* d_in, const int* in_sizes, int n_in,
                              void* d_out, int out_size, void* d_ws, size_t ws_size,
                              hipStream_t stream) {
    const float* feat = (const float*)d_in[0];
    const int*   rows = (const int*)d_in[1];
    const int*   cols = (const int*)d_in[2];
    const float* vals = (const float*)d_in[3];
    const float* W0   = (const float*)d_in[4];
    const float* W1   = (const float*)d_in[5];
    const float* W2   = (const float*)d_in[6];
    const float* W3   = (const float*)d_in[7];
    const float* s1   = (const float*)d_in[8];
    const float* s2   = (const float*)d_in[9];
    float* out = (float*)d_out;
    int E = in_sizes[1];

    float* ws   = (float*)d_ws;
    float* xw0  = ws;                          // 262144 floats
    float* Y    = ws + 262144;                 // N*48 = 393216 floats
    float* z    = ws + 655360;                 // 131072 floats
    int*   deg  = (int*)(ws + 786432);         // 8192 ints
    int2*  ell  = (int2*)(ws + 794624);        // 8192*64 int2 (byte off 3178496 % 8 == 0)

    k_xw0        <<<N_NODES / 32, 256, 0, stream>>>(feat, W0, xw0, deg);
    k_scatter_ell<<<(E + 255) / 256, 256, 0, stream>>>(rows, cols, vals, deg, ell, E);
    k_spmm1h     <<<N_NODES * 16 / 256, 256, 0, stream>>>(deg, ell, xw0, W1, W2, W3, Y);
    k_spmm3f     <<<N_NODES * 16 / 256, 256, 0, stream>>>(deg, ell, Y, s1, s2, z);

    dim3 grid(N_NODES / 256, N_NODES / 16);
    k_zzt<<<grid, 256, 0, stream>>>(z, out);
}